// Round 1
// baseline (127599.219 us; speedup 1.0000x reference)
//
#include <hip/hip_runtime.h>
#include <math.h>

#define N_BUS 2000
#define N_EDGE 6000
#define N2 4000
#define NB 64
#define NPANELS 35
#define MPAD (NB * NPANELS) /* 2240 */
#define LD 2304
#define T_STEPS 5
#define EPSR 1e-6f

// Workspace layout (floats):
//  M      : MPAD*LD          (augmented reduced matrix, RHS in col MPAD)
//  dx     : MPAD
//  dxc    : N2    (known dx for dropped coords)
//  va,vm  : N_BUS each
//  Pacc,Qacc : N_BUS each
//  gsa,bsa: N_EDGE each (series admittance)
//  kmap   : N2 ints (orig index -> reduced index or -1)
//  ipiv   : NB ints
//  m_dev  : 1 int
// total ~20.8 MB

__global__ __launch_bounds__(1024) void prep_once_kernel(
    const float* __restrict__ x, const int* __restrict__ bus_type,
    const float* __restrict__ br_r, const float* __restrict__ br_x,
    float* va, float* vm, float* gsa, float* bsa, int* kmap, int* m_dev) {
  const int tid = threadIdx.x;
  if (tid == 0) {
    int m = 0;
    for (int j = 0; j < N2; ++j) {
      bool kept = (j < N_BUS) ? (bus_type[j] != 3) : (bus_type[j - N_BUS] == 1);
      kmap[j] = kept ? m++ : -1;
    }
    *m_dev = m;  // expected ~2000, padded rows [m, MPAD) become identity
  }
  for (int e = tid; e < N_EDGE; e += 1024) {
    float r = br_r[e], xx = br_x[e];
    float den = r * r + xx * xx;
    gsa[e] = r / den;
    bsa[e] = -xx / den;
  }
  for (int i = tid; i < N_BUS; i += 1024) {
    va[i] = x[i];
    vm[i] = x[N_BUS + i];
  }
}

__global__ void step_prep_kernel(const int* __restrict__ bus_type,
                                 const float* __restrict__ vsp,
                                 const float* __restrict__ va,
                                 const float* __restrict__ vm,
                                 float* dxc, float* Pacc, float* Qacc) {
  int t = blockIdx.x * blockDim.x + threadIdx.x;
  if (t >= N2) return;
  if (t < N_BUS) {
    Pacc[t] = 0.f;
    Qacc[t] = 0.f;
    int bt = bus_type[t];
    dxc[t] = (bt == 3) ? va[t] / (1.f + EPSR) : 0.f;  // slack P-row: F=va
  } else {
    int i = t - N_BUS;
    int bt = bus_type[i];
    dxc[t] = (bt >= 2) ? (vm[i] - vsp[i]) / (1.f + EPSR) : 0.f;  // pv|sl Q-row
  }
}

__global__ void clear_M_kernel(float4* __restrict__ M4) {
  int t = blockIdx.x * blockDim.x + threadIdx.x;
  if (t < MPAD * LD / 4) M4[t] = float4{0.f, 0.f, 0.f, 0.f};
}

__device__ __forceinline__ void addJ(float* __restrict__ M,
                                     const int* __restrict__ kmap,
                                     const float* __restrict__ dxc, int r,
                                     int C, float v) {
  int c = kmap[C];
  if (c >= 0)
    atomicAdd(&M[(size_t)r * LD + c], v);
  else
    atomicAdd(&M[(size_t)r * LD + MPAD], -v * dxc[C]);  // move known col to RHS
}

__global__ void edge_kernel(const int* __restrict__ ei,
                            const float* __restrict__ gsa,
                            const float* __restrict__ bsa,
                            const float* __restrict__ g_fr,
                            const float* __restrict__ b_fr,
                            const float* __restrict__ g_to,
                            const float* __restrict__ b_to,
                            const float* __restrict__ tapA,
                            const float* __restrict__ shiftA,
                            const float* __restrict__ va,
                            const float* __restrict__ vm,
                            const int* __restrict__ kmap,
                            const float* __restrict__ dxc,
                            float* __restrict__ M, float* __restrict__ Pacc,
                            float* __restrict__ Qacc) {
  int e = blockIdx.x * blockDim.x + threadIdx.x;
  if (e >= N_EDGE) return;
  int s = ei[e], d = ei[N_EDGE + e];
  float g = gsa[e], b = bsa[e];
  float ti = 1.f / tapA[e];
  float vi = vm[s], vj = vm[d];
  float th = (va[s] - va[d]) - shiftA[e];
  float cf = cosf(th), sf = sinf(th);
  float vij = vi * vj * ti;
  float Af = g * cf + b * sf, Bf = g * sf - b * cf;
  float At = g * cf - b * sf, Bt = -g * sf - b * cf;  // cos_t=cf, sin_t=-sf
  float vit = vi * ti;
  float Pf = vit * vit * (g + g_fr[e]) + vij * (-g * cf - b * sf);
  float Qf = -vit * vit * (b + b_fr[e]) + vij * (-g * sf + b * cf);
  float Pt = vj * vj * (g + g_to[e]) + vij * (-g * cf + b * sf);
  float Qt = -vj * vj * (b + b_to[e]) + vij * (g * sf + b * cf);
  atomicAdd(&Pacc[s], Pf);
  atomicAdd(&Qacc[s], Qf);
  atomicAdd(&Pacc[d], Pt);
  atomicAdd(&Qacc[d], Qt);
  int rPs = kmap[s], rPd = kmap[d];
  int rQs = kmap[N_BUS + s], rQd = kmap[N_BUS + d];
  if (rPs >= 0) {
    addJ(M, kmap, dxc, rPs, s, -vij * Bf);
    addJ(M, kmap, dxc, rPs, d, vij * Bf);
    addJ(M, kmap, dxc, rPs, N_BUS + s,
         -2.f * vi * ti * ti * (g + g_fr[e]) + vj * ti * Af);
    addJ(M, kmap, dxc, rPs, N_BUS + d, vi * ti * Af);
  }
  if (rQs >= 0) {
    addJ(M, kmap, dxc, rQs, s, vij * Af);
    addJ(M, kmap, dxc, rQs, d, -vij * Af);
    addJ(M, kmap, dxc, rQs, N_BUS + s,
         2.f * vi * ti * ti * (b + b_fr[e]) + vj * ti * Bf);
    addJ(M, kmap, dxc, rQs, N_BUS + d, vi * ti * Bf);
  }
  if (rPd >= 0) {
    addJ(M, kmap, dxc, rPd, d, -vij * Bt);
    addJ(M, kmap, dxc, rPd, s, vij * Bt);
    addJ(M, kmap, dxc, rPd, N_BUS + d,
         -2.f * vj * (g + g_to[e]) + vi * ti * At);
    addJ(M, kmap, dxc, rPd, N_BUS + s, vj * ti * At);
  }
  if (rQd >= 0) {
    addJ(M, kmap, dxc, rQd, d, vij * At);
    addJ(M, kmap, dxc, rQd, s, -vij * At);
    addJ(M, kmap, dxc, rQd, N_BUS + d,
         2.f * vj * (b + b_to[e]) + vi * ti * Bt);
    addJ(M, kmap, dxc, rQd, N_BUS + s, vj * ti * Bt);
  }
}

__global__ void finalize_kernel(const float* __restrict__ p_spec,
                                const float* __restrict__ q_spec,
                                const float* __restrict__ gsN,
                                const float* __restrict__ bsN,
                                const float* __restrict__ va,
                                const float* __restrict__ vm,
                                const int* __restrict__ kmap,
                                const float* __restrict__ dxc,
                                const int* __restrict__ m_dev,
                                float* __restrict__ M,
                                const float* __restrict__ Pacc,
                                const float* __restrict__ Qacc) {
  int t = blockIdx.x * blockDim.x + threadIdx.x;
  if (t < N_BUS) {
    int r = kmap[t];
    if (r >= 0) {
      float* row = &M[(size_t)r * LD];
      row[r] += EPSR;
      int cq = kmap[N_BUS + t];
      float val = -2.f * vm[t] * gsN[t];  // dFP_dvm diagonal term
      if (cq >= 0)
        row[cq] += val;
      else
        row[MPAD] -= val * dxc[N_BUS + t];
      float Pc = Pacc[t] + vm[t] * vm[t] * gsN[t];
      row[MPAD] += p_spec[t] - Pc;  // F_p
    }
  } else if (t < N2) {
    int i = t - N_BUS;
    int r = kmap[t];
    if (r >= 0) {
      float* row = &M[(size_t)r * LD];
      row[r] += 2.f * vm[i] * bsN[i] + EPSR;  // dFQ_dvm diag + eps
      float Qc = Qacc[i] - vm[i] * vm[i] * bsN[i];
      row[MPAD] += q_spec[i] - Qc;  // F_q
    }
  } else if (t < N2 + MPAD) {
    int r = t - N2;
    if (r >= *m_dev) M[(size_t)r * LD + r] = 1.f;  // identity padding
  }
}

// Panel LU with partial pivoting; panel held in registers, swaps by
// position-label exchange. Single block of 1024 threads, 3 rows/thread.
__global__ __launch_bounds__(1024) void panel_kernel(float* __restrict__ M,
                                                     int pan,
                                                     int* __restrict__ ipiv) {
  const int s0 = pan * NB;
  const int tid = threadIdx.x;
  __shared__ float s_piv[NB];
  __shared__ float s_rv[16];
  __shared__ int s_ri[16];
  __shared__ int s_p;
  float a[3][NB];
  int pos[3];
  bool val[3];
#pragma unroll
  for (int k = 0; k < 3; ++k) {
    int rg = s0 + tid + k * 1024;
    pos[k] = rg;
    val[k] = rg < MPAD;
    if (val[k]) {
      const float* src = &M[(size_t)rg * LD + s0];
#pragma unroll
      for (int c = 0; c < NB; ++c) a[k][c] = src[c];
    } else {
#pragma unroll
      for (int c = 0; c < NB; ++c) a[k][c] = 0.f;
    }
  }
  const int wid = tid >> 6, lane = tid & 63;
#pragma unroll
  for (int j = 0; j < NB; ++j) {
    const int jg = s0 + j;
    // local argmax over owned active rows
    float bv = -1.f;
    int bi = 0x7fffffff;
#pragma unroll
    for (int k = 0; k < 3; ++k) {
      bool act = val[k] && (pos[k] >= jg);
      float v = fabsf(a[k][j]);
      if (act && (v > bv || (v == bv && pos[k] < bi))) {
        bv = v;
        bi = pos[k];
      }
    }
#pragma unroll
    for (int off = 32; off >= 1; off >>= 1) {
      float ov = __shfl_down(bv, off, 64);
      int oi = __shfl_down(bi, off, 64);
      if (ov > bv || (ov == bv && oi < bi)) {
        bv = ov;
        bi = oi;
      }
    }
    if (lane == 0) {
      s_rv[wid] = bv;
      s_ri[wid] = bi;
    }
    __syncthreads();  // (1)
    if (wid == 0) {
      float v2 = (lane < 16) ? s_rv[lane] : -1.f;
      int i2 = (lane < 16) ? s_ri[lane] : 0x7fffffff;
#pragma unroll
      for (int off = 8; off >= 1; off >>= 1) {
        float ov = __shfl_down(v2, off, 64);
        int oi = __shfl_down(i2, off, 64);
        if (ov > v2 || (ov == v2 && oi < i2)) {
          v2 = ov;
          i2 = oi;
        }
      }
      if (lane == 0) {
        s_p = i2;
        ipiv[j] = i2;
      }
    }
    __syncthreads();  // (2)
    const int p = s_p;
    // pivot-row broadcast + label swap (no data movement)
#pragma unroll
    for (int k = 0; k < 3; ++k) {
      bool isj = val[k] && (pos[k] == jg);
      bool isp = val[k] && (pos[k] == p);
      if (isp) {
#pragma unroll
        for (int c = j; c < NB; ++c) s_piv[c] = a[k][c];
      }
      if (isj) pos[k] = p;
      if (isp) pos[k] = jg;
    }
    __syncthreads();  // (3)
    float piv = s_piv[j];
    float rinv = (piv != 0.f) ? (1.f / piv) : 0.f;
#pragma unroll
    for (int k = 0; k < 3; ++k) {
      bool act = val[k] && (pos[k] > jg);
      float l = a[k][j] * rinv;
      if (act) {
        a[k][j] = l;
#pragma unroll
        for (int c = j + 1; c < NB; ++c)
          a[k][c] = fmaf(-l, s_piv[c], a[k][c]);
      }
    }
    __syncthreads();  // protect s_piv/s_rv for next column
  }
#pragma unroll
  for (int k = 0; k < 3; ++k) {
    if (val[k]) {
      float* dst = &M[(size_t)pos[k] * LD + s0];
#pragma unroll
      for (int c = 0; c < NB; ++c) dst[c] = a[k][c];
    }
  }
}

// Apply row swaps to trailing columns (incl RHS) and TRSM the block row.
__global__ __launch_bounds__(256) void swap_trsm_kernel(
    float* __restrict__ M, int pan, const int* __restrict__ ipiv) {
  const int s0 = pan * NB, s1 = s0 + NB;
  const int c = s1 + blockIdx.x * 256 + threadIdx.x;
  __shared__ int s_piv[NB];
  __shared__ __align__(16) float Ls[NB][NB + 1];
  if (threadIdx.x < NB) s_piv[threadIdx.x] = ipiv[threadIdx.x];
  for (int idx = threadIdx.x; idx < NB * NB; idx += 256) {
    int i = idx >> 6, jj = idx & 63;
    Ls[i][jj] = M[(size_t)(s0 + i) * LD + s0 + jj];
  }
  __syncthreads();
  if (c > MPAD) return;  // RHS col == MPAD inclusive
  for (int i = 0; i < NB; ++i) {
    int p = s_piv[i];
    if (p != s0 + i) {
      float t1 = M[(size_t)(s0 + i) * LD + c];
      M[(size_t)(s0 + i) * LD + c] = M[(size_t)p * LD + c];
      M[(size_t)p * LD + c] = t1;
    }
  }
  float y[NB];
#pragma unroll
  for (int i = 0; i < NB; ++i) y[i] = M[(size_t)(s0 + i) * LD + c];
#pragma unroll
  for (int i = 1; i < NB; ++i)
#pragma unroll
    for (int jj = 0; jj < NB; ++jj) {
      if (jj < i) y[i] = fmaf(-Ls[i][jj], y[jj], y[i]);
    }
#pragma unroll
  for (int i = 0; i < NB; ++i) M[(size_t)(s0 + i) * LD + c] = y[i];
}

__global__ __launch_bounds__(256) void gemm_update_kernel(
    float* __restrict__ M, int pan) {
  const int s0 = pan * NB, s1 = s0 + NB;
  const int r0 = s1 + blockIdx.x * 64;
  const int c0 = s1 + blockIdx.y * 64;
  __shared__ __align__(16) float As[64][68];
  __shared__ __align__(16) float Bs[64][68];
  const int tid = threadIdx.x;
  for (int idx = tid; idx < 64 * 64; idx += 256) {
    int i = idx >> 6, jj = idx & 63;
    As[i][jj] = M[(size_t)(r0 + i) * LD + s0 + jj];  // A21[r][k]
    Bs[i][jj] = M[(size_t)(s0 + i) * LD + c0 + jj];  // B[k][c]
  }
  __syncthreads();
  const int tr = (tid >> 4) * 4;
  const int tc = (tid & 15) * 4;
  float acc[4][4] = {};
#pragma unroll
  for (int k4 = 0; k4 < 16; ++k4) {
    float ar[4][4], br[4][4];
#pragma unroll
    for (int i = 0; i < 4; ++i) {
      float4 t = *(const float4*)&As[tr + i][k4 * 4];
      ar[i][0] = t.x; ar[i][1] = t.y; ar[i][2] = t.z; ar[i][3] = t.w;
    }
#pragma unroll
    for (int kk = 0; kk < 4; ++kk) {
      float4 t = *(const float4*)&Bs[k4 * 4 + kk][tc];
      br[kk][0] = t.x; br[kk][1] = t.y; br[kk][2] = t.z; br[kk][3] = t.w;
    }
#pragma unroll
    for (int kk = 0; kk < 4; ++kk)
#pragma unroll
      for (int i = 0; i < 4; ++i)
#pragma unroll
        for (int jj = 0; jj < 4; ++jj)
          acc[i][jj] = fmaf(ar[i][kk], br[kk][jj], acc[i][jj]);
  }
#pragma unroll
  for (int i = 0; i < 4; ++i) {
    float* crow = &M[(size_t)(r0 + tr + i) * LD + c0 + tc];
    float4 cv = *(float4*)crow;
    cv.x -= acc[i][0];
    cv.y -= acc[i][1];
    cv.z -= acc[i][2];
    cv.w -= acc[i][3];
    *(float4*)crow = cv;
  }
}

__global__ __launch_bounds__(1024) void backsub_kernel(
    const float* __restrict__ M, float* __restrict__ dx) {
  __shared__ float ys[MPAD];
  __shared__ float Ds[NB][NB + 1];
  __shared__ float Dinv[NB];
  const int tid = threadIdx.x;
  for (int r = tid; r < MPAD; r += 1024) ys[r] = M[(size_t)r * LD + MPAD];
  __syncthreads();
  for (int jb = NPANELS - 1; jb >= 0; --jb) {
    const int b0 = jb * NB;
    for (int idx = tid; idx < NB * NB; idx += 1024) {
      int i = idx >> 6, jj = idx & 63;
      Ds[i][jj] = M[(size_t)(b0 + i) * LD + b0 + jj];
    }
    __syncthreads();
    if (tid < NB) Dinv[tid] = 1.f / Ds[tid][tid];
    __syncthreads();
    if (tid < NB) {
      for (int i = NB - 1; i >= 0; --i) {
        float xv = ys[b0 + i] * Dinv[i];
        if (tid == i) ys[b0 + i] = xv;
        else if (tid < i) ys[b0 + tid] = fmaf(-Ds[tid][i], xv, ys[b0 + tid]);
      }
    }
    __syncthreads();
    const int wid = tid >> 6, lane = tid & 63;
    float xv = ys[b0 + lane];
    for (int r = wid * 4; r + 3 < b0 + 1 && r < b0; r += 64) {
      float a0 = M[(size_t)(r + 0) * LD + b0 + lane] * xv;
      float a1 = M[(size_t)(r + 1) * LD + b0 + lane] * xv;
      float a2 = M[(size_t)(r + 2) * LD + b0 + lane] * xv;
      float a3 = M[(size_t)(r + 3) * LD + b0 + lane] * xv;
#pragma unroll
      for (int off = 32; off >= 1; off >>= 1) {
        a0 += __shfl_down(a0, off, 64);
        a1 += __shfl_down(a1, off, 64);
        a2 += __shfl_down(a2, off, 64);
        a3 += __shfl_down(a3, off, 64);
      }
      if (lane == 0) {
        ys[r + 0] -= a0;
        ys[r + 1] -= a1;
        ys[r + 2] -= a2;
        ys[r + 3] -= a3;
      }
    }
    __syncthreads();
  }
  for (int r = tid; r < MPAD; r += 1024) dx[r] = ys[r];
}

__global__ void update_kernel(const int* __restrict__ kmap,
                              const float* __restrict__ dx,
                              const float* __restrict__ dxc, float* va,
                              float* vm, float* __restrict__ out) {
  int t = blockIdx.x * blockDim.x + threadIdx.x;
  if (t >= N2) return;
  int r = kmap[t];
  float d = (r >= 0) ? dx[r] : dxc[t];
  if (t < N_BUS) {
    float v = va[t] - d;
    va[t] = v;
    out[t] = v;
  } else {
    int i = t - N_BUS;
    float v = vm[i] - d;
    v = fminf(fmaxf(v, 0.5f), 1.5f);
    vm[i] = v;
    out[t] = v;
  }
}

extern "C" void kernel_launch(void* const* d_in, const int* in_sizes, int n_in,
                              void* d_out, int out_size, void* d_ws,
                              size_t ws_size, hipStream_t stream) {
  const float* x = (const float*)d_in[0];
  const int* ei = (const int*)d_in[1];
  const float* br_r = (const float*)d_in[2];
  const float* br_x = (const float*)d_in[3];
  const float* g_fr = (const float*)d_in[4];
  const float* b_fr = (const float*)d_in[5];
  const float* g_to = (const float*)d_in[6];
  const float* b_to = (const float*)d_in[7];
  const float* tap = (const float*)d_in[8];
  const float* shift = (const float*)d_in[9];
  const float* p_spec = (const float*)d_in[10];
  const float* q_spec = (const float*)d_in[11];
  const float* gsN = (const float*)d_in[12];
  const float* bsN = (const float*)d_in[13];
  const int* bus_type = (const int*)d_in[14];
  const float* vsp = (const float*)d_in[15];
  float* out = (float*)d_out;

  float* W = (float*)d_ws;
  float* M = W;
  float* dx = W + (size_t)MPAD * LD;
  float* dxc = dx + MPAD;
  float* va = dxc + N2;
  float* vm = va + N_BUS;
  float* Pacc = vm + N_BUS;
  float* Qacc = Pacc + N_BUS;
  float* gsa = Qacc + N_BUS;
  float* bsa = gsa + N_EDGE;
  int* kmap = (int*)(bsa + N_EDGE);
  int* ipiv = kmap + N2;
  int* m_dev = ipiv + NB;

  prep_once_kernel<<<1, 1024, 0, stream>>>(x, bus_type, br_r, br_x, va, vm,
                                           gsa, bsa, kmap, m_dev);
  for (int t = 0; t < T_STEPS; ++t) {
    step_prep_kernel<<<(N2 + 255) / 256, 256, 0, stream>>>(bus_type, vsp, va,
                                                           vm, dxc, Pacc, Qacc);
    clear_M_kernel<<<(MPAD * LD / 4 + 255) / 256, 256, 0, stream>>>(
        (float4*)M);
    edge_kernel<<<(N_EDGE + 255) / 256, 256, 0, stream>>>(
        ei, gsa, bsa, g_fr, b_fr, g_to, b_to, tap, shift, va, vm, kmap, dxc, M,
        Pacc, Qacc);
    finalize_kernel<<<(N2 + MPAD + 255) / 256, 256, 0, stream>>>(
        p_spec, q_spec, gsN, bsN, va, vm, kmap, dxc, m_dev, M, Pacc, Qacc);
    for (int p = 0; p < NPANELS; ++p) {
      panel_kernel<<<1, 1024, 0, stream>>>(M, p, ipiv);
      int s1 = (p + 1) * NB;
      int w = MPAD - s1 + 1;  // trailing cols incl RHS
      swap_trsm_kernel<<<(w + 255) / 256, 256, 0, stream>>>(M, p, ipiv);
      int tr_ = NPANELS - 1 - p;
      int tc_ = NPANELS - p;
      if (tr_ > 0) {
        dim3 g(tr_, tc_);
        gemm_update_kernel<<<g, 256, 0, stream>>>(M, p);
      }
    }
    backsub_kernel<<<1, 1024, 0, stream>>>(M, dx);
    update_kernel<<<(N2 + 255) / 256, 256, 0, stream>>>(kmap, dx, dxc, va, vm,
                                                        out);
  }
}

// Round 2
// 27619.965 us; speedup vs baseline: 4.6198x; 4.6198x over previous
//
#include <hip/hip_runtime.h>
#include <math.h>

#define N_BUS 2000
#define N_EDGE 6000
#define N2 4000
#define NB 64
#define NPANELS 35
#define MPAD (NB * NPANELS) /* 2240 */
#define LD 2308
#define DCOL 2241 /* factored diag blocks stored at cols [DCOL, DCOL+64) */
#define T_STEPS 5
#define EPSR 1e-6f

__global__ __launch_bounds__(1024) void prep_once_kernel(
    const float* __restrict__ x, const int* __restrict__ bus_type,
    const float* __restrict__ br_r, const float* __restrict__ br_x,
    float* va, float* vm, float* gsa, float* bsa, int* kmap, int* m_dev) {
  const int tid = threadIdx.x;
  if (tid == 0) {
    int m = 0;
    for (int j = 0; j < N2; ++j) {
      bool kept = (j < N_BUS) ? (bus_type[j] != 3) : (bus_type[j - N_BUS] == 1);
      kmap[j] = kept ? m++ : -1;
    }
    *m_dev = m;
  }
  for (int e = tid; e < N_EDGE; e += 1024) {
    float r = br_r[e], xx = br_x[e];
    float den = r * r + xx * xx;
    gsa[e] = r / den;
    bsa[e] = -xx / den;
  }
  for (int i = tid; i < N_BUS; i += 1024) {
    va[i] = x[i];
    vm[i] = x[N_BUS + i];
  }
}

__global__ void step_prep_kernel(const int* __restrict__ bus_type,
                                 const float* __restrict__ vsp,
                                 const float* __restrict__ va,
                                 const float* __restrict__ vm,
                                 float* dxc, float* Pacc, float* Qacc) {
  int t = blockIdx.x * blockDim.x + threadIdx.x;
  if (t >= N2) return;
  if (t < N_BUS) {
    Pacc[t] = 0.f;
    Qacc[t] = 0.f;
    int bt = bus_type[t];
    dxc[t] = (bt == 3) ? va[t] / (1.f + EPSR) : 0.f;
  } else {
    int i = t - N_BUS;
    int bt = bus_type[i];
    dxc[t] = (bt >= 2) ? (vm[i] - vsp[i]) / (1.f + EPSR) : 0.f;
  }
}

__global__ void clear_M_kernel(float4* __restrict__ M4) {
  int t = blockIdx.x * blockDim.x + threadIdx.x;
  if (t < MPAD * LD / 4) M4[t] = float4{0.f, 0.f, 0.f, 0.f};
}

__device__ __forceinline__ void addJ(float* __restrict__ M,
                                     const int* __restrict__ kmap,
                                     const float* __restrict__ dxc, int r,
                                     int C, float v) {
  int c = kmap[C];
  if (c >= 0)
    atomicAdd(&M[(size_t)r * LD + c], v);
  else
    atomicAdd(&M[(size_t)r * LD + MPAD], -v * dxc[C]);
}

__global__ void edge_kernel(const int* __restrict__ ei,
                            const float* __restrict__ gsa,
                            const float* __restrict__ bsa,
                            const float* __restrict__ g_fr,
                            const float* __restrict__ b_fr,
                            const float* __restrict__ g_to,
                            const float* __restrict__ b_to,
                            const float* __restrict__ tapA,
                            const float* __restrict__ shiftA,
                            const float* __restrict__ va,
                            const float* __restrict__ vm,
                            const int* __restrict__ kmap,
                            const float* __restrict__ dxc,
                            float* __restrict__ M, float* __restrict__ Pacc,
                            float* __restrict__ Qacc) {
  int e = blockIdx.x * blockDim.x + threadIdx.x;
  if (e >= N_EDGE) return;
  int s = ei[e], d = ei[N_EDGE + e];
  float g = gsa[e], b = bsa[e];
  float ti = 1.f / tapA[e];
  float vi = vm[s], vj = vm[d];
  float th = (va[s] - va[d]) - shiftA[e];
  float cf = cosf(th), sf = sinf(th);
  float vij = vi * vj * ti;
  float Af = g * cf + b * sf, Bf = g * sf - b * cf;
  float At = g * cf - b * sf, Bt = -g * sf - b * cf;
  float vit = vi * ti;
  float Pf = vit * vit * (g + g_fr[e]) + vij * (-g * cf - b * sf);
  float Qf = -vit * vit * (b + b_fr[e]) + vij * (-g * sf + b * cf);
  float Pt = vj * vj * (g + g_to[e]) + vij * (-g * cf + b * sf);
  float Qt = -vj * vj * (b + b_to[e]) + vij * (g * sf + b * cf);
  atomicAdd(&Pacc[s], Pf);
  atomicAdd(&Qacc[s], Qf);
  atomicAdd(&Pacc[d], Pt);
  atomicAdd(&Qacc[d], Qt);
  int rPs = kmap[s], rPd = kmap[d];
  int rQs = kmap[N_BUS + s], rQd = kmap[N_BUS + d];
  if (rPs >= 0) {
    addJ(M, kmap, dxc, rPs, s, -vij * Bf);
    addJ(M, kmap, dxc, rPs, d, vij * Bf);
    addJ(M, kmap, dxc, rPs, N_BUS + s,
         -2.f * vi * ti * ti * (g + g_fr[e]) + vj * ti * Af);
    addJ(M, kmap, dxc, rPs, N_BUS + d, vi * ti * Af);
  }
  if (rQs >= 0) {
    addJ(M, kmap, dxc, rQs, s, vij * Af);
    addJ(M, kmap, dxc, rQs, d, -vij * Af);
    addJ(M, kmap, dxc, rQs, N_BUS + s,
         2.f * vi * ti * ti * (b + b_fr[e]) + vj * ti * Bf);
    addJ(M, kmap, dxc, rQs, N_BUS + d, vi * ti * Bf);
  }
  if (rPd >= 0) {
    addJ(M, kmap, dxc, rPd, d, -vij * Bt);
    addJ(M, kmap, dxc, rPd, s, vij * Bt);
    addJ(M, kmap, dxc, rPd, N_BUS + d,
         -2.f * vj * (g + g_to[e]) + vi * ti * At);
    addJ(M, kmap, dxc, rPd, N_BUS + s, vj * ti * At);
  }
  if (rQd >= 0) {
    addJ(M, kmap, dxc, rQd, d, vij * At);
    addJ(M, kmap, dxc, rQd, s, -vij * At);
    addJ(M, kmap, dxc, rQd, N_BUS + d,
         2.f * vj * (b + b_to[e]) + vi * ti * Bt);
    addJ(M, kmap, dxc, rQd, N_BUS + s, vj * ti * Bt);
  }
}

__global__ void finalize_kernel(const float* __restrict__ p_spec,
                                const float* __restrict__ q_spec,
                                const float* __restrict__ gsN,
                                const float* __restrict__ bsN,
                                const float* __restrict__ va,
                                const float* __restrict__ vm,
                                const int* __restrict__ kmap,
                                const float* __restrict__ dxc,
                                const int* __restrict__ m_dev,
                                float* __restrict__ M,
                                const float* __restrict__ Pacc,
                                const float* __restrict__ Qacc) {
  int t = blockIdx.x * blockDim.x + threadIdx.x;
  if (t < N_BUS) {
    int r = kmap[t];
    if (r >= 0) {
      float* row = &M[(size_t)r * LD];
      row[r] += EPSR;
      int cq = kmap[N_BUS + t];
      float val = -2.f * vm[t] * gsN[t];
      if (cq >= 0)
        row[cq] += val;
      else
        row[MPAD] -= val * dxc[N_BUS + t];
      float Pc = Pacc[t] + vm[t] * vm[t] * gsN[t];
      row[MPAD] += p_spec[t] - Pc;
    }
  } else if (t < N2) {
    int i = t - N_BUS;
    int r = kmap[t];
    if (r >= 0) {
      float* row = &M[(size_t)r * LD];
      row[r] += 2.f * vm[i] * bsN[i] + EPSR;
      float Qc = Qacc[i] - vm[i] * vm[i] * bsN[i];
      row[MPAD] += q_spec[i] - Qc;
    }
  } else if (t < N2 + MPAD) {
    int r = t - N2;
    if (r >= *m_dev) M[(size_t)r * LD + r] = 1.f;
  }
}

// Fused per-panel kernel. Every block redundantly factors the 64x64 diagonal
// block in LDS with in-block partial pivoting, then:
//   blocks [0, ncolblk)    : row-permute + L-forward-solve trailing columns
//                            (incl. the RHS column at MPAD); block 0 also
//                            stores the factored diag to M[., DCOL..].
//   blocks [ncolblk, ...)  : compute L21 = A21 * U11^-1 for rows below.
__global__ __launch_bounds__(256) void panel_trsm_kernel(float* __restrict__ M,
                                                         int pan, int ncolblk) {
  const int s0 = pan * NB, s1 = s0 + NB;
  const int tid = threadIdx.x;
  __shared__ float Ls[NB][NB + 1];
  __shared__ int permS[NB];
  __shared__ float s_dinv[NB];
  __shared__ int s_p;
  __shared__ float s_kk, s_pk;

  for (int idx = tid; idx < NB * NB; idx += 256)
    Ls[idx >> 6][idx & 63] = M[(size_t)(s0 + (idx >> 6)) * LD + s0 + (idx & 63)];
  if (tid < NB) permS[tid] = tid;
  __syncthreads();

#pragma unroll 1
  for (int k = 0; k < NB; ++k) {
    // argmax |Ls[r][k]| over r in [k,63] — wave 0
    if (tid < 64) {
      float v = (tid >= k) ? fabsf(Ls[tid][k]) : -1.f;
      int bi = tid;
#pragma unroll
      for (int off = 32; off >= 1; off >>= 1) {
        float ov = __shfl_down(v, off, 64);
        int oi = __shfl_down(bi, off, 64);
        if (ov > v || (ov == v && oi < bi)) {
          v = ov;
          bi = oi;
        }
      }
      if (tid == 0) {
        s_p = bi;
        s_kk = Ls[k][k];
        s_pk = Ls[bi][k];
        int t = permS[k];
        permS[k] = permS[bi];
        permS[bi] = t;
      }
    }
    __syncthreads();
    const int p = s_p;
    const float pivinv = 1.f / s_pk;
    if (tid < 64) {
      // row swap (cols), using broadcast scalars to avoid RAW with the
      // multiplier writes below; element (p,k) is written by the mult path.
      if (p != k) {
        int c = tid;
        float tk = Ls[k][c];
        float nk = (c == k) ? s_pk : Ls[p][c];
        Ls[k][c] = nk;
        if (c != k) Ls[p][c] = tk;
      }
      // multipliers for column k (pre-swap semantics via s_kk)
      int r = tid;
      if (r > k) {
        float vr = (r == p) ? s_kk : Ls[r][k];
        Ls[r][k] = vr * pivinv;
      }
    }
    __syncthreads();
    // rank-1 trailing update
    {
      int c = tid & 63;
      if (c > k) {
        float ukc = Ls[k][c];
        for (int r = k + 1 + (tid >> 6); r < NB; r += 4)
          Ls[r][c] = fmaf(-Ls[r][k], ukc, Ls[r][c]);
      }
    }
    __syncthreads();
  }
  if (tid < NB) s_dinv[tid] = 1.f / Ls[tid][tid];
  __syncthreads();

  if (blockIdx.x < ncolblk) {
    if (blockIdx.x == 0) {
      for (int idx = tid; idx < NB * NB; idx += 256)
        M[(size_t)(s0 + (idx >> 6)) * LD + DCOL + (idx & 63)] =
            Ls[idx >> 6][idx & 63];
    }
    int c = s1 + blockIdx.x * 256 + tid;
    if (c <= MPAD) {
      float y[NB];
#pragma unroll
      for (int i = 0; i < NB; ++i)
        y[i] = M[(size_t)(s0 + permS[i]) * LD + c];
#pragma unroll
      for (int i = 1; i < NB; ++i)
#pragma unroll
        for (int j = 0; j < i; ++j) y[i] = fmaf(-Ls[i][j], y[j], y[i]);
#pragma unroll
      for (int i = 0; i < NB; ++i) M[(size_t)(s0 + i) * LD + c] = y[i];
    }
  } else {
    int r = s1 + (blockIdx.x - ncolblk) * 256 + tid;
    if (r < MPAD) {
      float a[NB];
#pragma unroll
      for (int j4 = 0; j4 < NB / 4; ++j4) {
        float4 t = *(const float4*)&M[(size_t)r * LD + s0 + j4 * 4];
        a[j4 * 4 + 0] = t.x;
        a[j4 * 4 + 1] = t.y;
        a[j4 * 4 + 2] = t.z;
        a[j4 * 4 + 3] = t.w;
      }
#pragma unroll
      for (int j = 0; j < NB; ++j) {
#pragma unroll
        for (int k = 0; k < j; ++k) a[j] = fmaf(-a[k], Ls[k][j], a[j]);
        a[j] *= s_dinv[j];
      }
#pragma unroll
      for (int j4 = 0; j4 < NB / 4; ++j4) {
        float4 t;
        t.x = a[j4 * 4 + 0];
        t.y = a[j4 * 4 + 1];
        t.z = a[j4 * 4 + 2];
        t.w = a[j4 * 4 + 3];
        *(float4*)&M[(size_t)r * LD + s0 + j4 * 4] = t;
      }
    }
  }
}

__global__ __launch_bounds__(256) void gemm_update_kernel(
    float* __restrict__ M, int pan) {
  const int s0 = pan * NB, s1 = s0 + NB;
  const int r0 = s1 + blockIdx.x * 64;
  const int c0 = s1 + blockIdx.y * 64;
  __shared__ __align__(16) float As[64][68];
  __shared__ __align__(16) float Bs[64][68];
  const int tid = threadIdx.x;
  for (int idx = tid; idx < 64 * 16; idx += 256) {
    int i = idx >> 4, j4 = idx & 15;
    *(float4*)&As[i][j4 * 4] =
        *(const float4*)&M[(size_t)(r0 + i) * LD + s0 + j4 * 4];
    *(float4*)&Bs[i][j4 * 4] =
        *(const float4*)&M[(size_t)(s0 + i) * LD + c0 + j4 * 4];
  }
  __syncthreads();
  const int tr = (tid >> 4) * 4;
  const int tc = (tid & 15) * 4;
  float acc[4][4] = {};
#pragma unroll
  for (int k4 = 0; k4 < 16; ++k4) {
    float ar[4][4], br[4][4];
#pragma unroll
    for (int i = 0; i < 4; ++i) {
      float4 t = *(const float4*)&As[tr + i][k4 * 4];
      ar[i][0] = t.x; ar[i][1] = t.y; ar[i][2] = t.z; ar[i][3] = t.w;
    }
#pragma unroll
    for (int kk = 0; kk < 4; ++kk) {
      float4 t = *(const float4*)&Bs[k4 * 4 + kk][tc];
      br[kk][0] = t.x; br[kk][1] = t.y; br[kk][2] = t.z; br[kk][3] = t.w;
    }
#pragma unroll
    for (int kk = 0; kk < 4; ++kk)
#pragma unroll
      for (int i = 0; i < 4; ++i)
#pragma unroll
        for (int jj = 0; jj < 4; ++jj)
          acc[i][jj] = fmaf(ar[i][kk], br[kk][jj], acc[i][jj]);
  }
#pragma unroll
  for (int i = 0; i < 4; ++i) {
    float* crow = &M[(size_t)(r0 + tr + i) * LD + c0 + tc];
    float4 cv = *(float4*)crow;
    cv.x -= acc[i][0];
    cv.y -= acc[i][1];
    cv.z -= acc[i][2];
    cv.w -= acc[i][3];
    *(float4*)crow = cv;
  }
}

__global__ __launch_bounds__(1024) void backsub_kernel(
    const float* __restrict__ M, float* __restrict__ dx) {
  __shared__ float ys[MPAD];
  __shared__ float Ds[NB][NB + 1];
  __shared__ float Dinv[NB];
  const int tid = threadIdx.x;
  for (int r = tid; r < MPAD; r += 1024) ys[r] = M[(size_t)r * LD + MPAD];
  __syncthreads();
  for (int jb = NPANELS - 1; jb >= 0; --jb) {
    const int b0 = jb * NB;
    for (int idx = tid; idx < NB * NB; idx += 1024) {
      int i = idx >> 6, jj = idx & 63;
      Ds[i][jj] = M[(size_t)(b0 + i) * LD + DCOL + jj];
    }
    __syncthreads();
    if (tid < NB) Dinv[tid] = 1.f / Ds[tid][tid];
    __syncthreads();
    if (tid < NB) {
      for (int i = NB - 1; i >= 0; --i) {
        float xv = ys[b0 + i] * Dinv[i];
        if (tid == i) ys[b0 + i] = xv;
        else if (tid < i) ys[b0 + tid] = fmaf(-Ds[tid][i], xv, ys[b0 + tid]);
      }
    }
    __syncthreads();
    const int wid = tid >> 6, lane = tid & 63;
    float xv = ys[b0 + lane];
    for (int r = wid * 4; r < b0; r += 64) {
      float a0 = M[(size_t)(r + 0) * LD + b0 + lane] * xv;
      float a1 = M[(size_t)(r + 1) * LD + b0 + lane] * xv;
      float a2 = M[(size_t)(r + 2) * LD + b0 + lane] * xv;
      float a3 = M[(size_t)(r + 3) * LD + b0 + lane] * xv;
#pragma unroll
      for (int off = 32; off >= 1; off >>= 1) {
        a0 += __shfl_down(a0, off, 64);
        a1 += __shfl_down(a1, off, 64);
        a2 += __shfl_down(a2, off, 64);
        a3 += __shfl_down(a3, off, 64);
      }
      if (lane == 0) {
        ys[r + 0] -= a0;
        ys[r + 1] -= a1;
        ys[r + 2] -= a2;
        ys[r + 3] -= a3;
      }
    }
    __syncthreads();
  }
  for (int r = tid; r < MPAD; r += 1024) dx[r] = ys[r];
}

__global__ void update_kernel(const int* __restrict__ kmap,
                              const float* __restrict__ dx,
                              const float* __restrict__ dxc, float* va,
                              float* vm, float* __restrict__ out) {
  int t = blockIdx.x * blockDim.x + threadIdx.x;
  if (t >= N2) return;
  int r = kmap[t];
  float d = (r >= 0) ? dx[r] : dxc[t];
  if (t < N_BUS) {
    float v = va[t] - d;
    va[t] = v;
    out[t] = v;
  } else {
    int i = t - N_BUS;
    float v = vm[i] - d;
    v = fminf(fmaxf(v, 0.5f), 1.5f);
    vm[i] = v;
    out[t] = v;
  }
}

extern "C" void kernel_launch(void* const* d_in, const int* in_sizes, int n_in,
                              void* d_out, int out_size, void* d_ws,
                              size_t ws_size, hipStream_t stream) {
  const float* x = (const float*)d_in[0];
  const int* ei = (const int*)d_in[1];
  const float* br_r = (const float*)d_in[2];
  const float* br_x = (const float*)d_in[3];
  const float* g_fr = (const float*)d_in[4];
  const float* b_fr = (const float*)d_in[5];
  const float* g_to = (const float*)d_in[6];
  const float* b_to = (const float*)d_in[7];
  const float* tap = (const float*)d_in[8];
  const float* shift = (const float*)d_in[9];
  const float* p_spec = (const float*)d_in[10];
  const float* q_spec = (const float*)d_in[11];
  const float* gsN = (const float*)d_in[12];
  const float* bsN = (const float*)d_in[13];
  const int* bus_type = (const int*)d_in[14];
  const float* vsp = (const float*)d_in[15];
  float* out = (float*)d_out;

  float* W = (float*)d_ws;
  float* M = W;
  float* dx = W + (size_t)MPAD * LD;
  float* dxc = dx + MPAD;
  float* va = dxc + N2;
  float* vm = va + N_BUS;
  float* Pacc = vm + N_BUS;
  float* Qacc = Pacc + N_BUS;
  float* gsa = Qacc + N_BUS;
  float* bsa = gsa + N_EDGE;
  int* kmap = (int*)(bsa + N_EDGE);
  int* m_dev = kmap + N2;

  prep_once_kernel<<<1, 1024, 0, stream>>>(x, bus_type, br_r, br_x, va, vm,
                                           gsa, bsa, kmap, m_dev);
  for (int t = 0; t < T_STEPS; ++t) {
    step_prep_kernel<<<(N2 + 255) / 256, 256, 0, stream>>>(bus_type, vsp, va,
                                                           vm, dxc, Pacc, Qacc);
    clear_M_kernel<<<(MPAD * LD / 4 + 255) / 256, 256, 0, stream>>>(
        (float4*)M);
    edge_kernel<<<(N_EDGE + 255) / 256, 256, 0, stream>>>(
        ei, gsa, bsa, g_fr, b_fr, g_to, b_to, tap, shift, va, vm, kmap, dxc, M,
        Pacc, Qacc);
    finalize_kernel<<<(N2 + MPAD + 255) / 256, 256, 0, stream>>>(
        p_spec, q_spec, gsN, bsN, va, vm, kmap, dxc, m_dev, M, Pacc, Qacc);
    for (int p = 0; p < NPANELS; ++p) {
      int s1 = (p + 1) * NB;
      int w = MPAD - s1 + 1;             // trailing cols incl RHS
      int ncb = (w + 255) / 256;
      int nrb = (MPAD - s1 + 255) / 256; // rows below
      panel_trsm_kernel<<<ncb + nrb, 256, 0, stream>>>(M, p, ncb);
      int tr_ = NPANELS - 1 - p;
      int tc_ = NPANELS - p;
      if (tr_ > 0) {
        dim3 g(tr_, tc_);
        gemm_update_kernel<<<g, 256, 0, stream>>>(M, p);
      }
    }
    backsub_kernel<<<1, 1024, 0, stream>>>(M, dx);
    update_kernel<<<(N2 + 255) / 256, 256, 0, stream>>>(kmap, dx, dxc, va, vm,
                                                        out);
  }
}

// Round 3
// 14717.076 us; speedup vs baseline: 8.6701x; 1.8767x over previous
//
#include <hip/hip_runtime.h>
#include <math.h>

#define N_BUS 2000
#define N_EDGE 6000
#define N2 4000
#define NB 64
#define NPANELS 35
#define MPAD (NB * NPANELS) /* 2240 */
#define LD 2308
#define DCOL 2244 /* LU tiles (L below unit diag, U on/above) at cols [DCOL, DCOL+64) */
#define T_STEPS 5
#define EPSR 1e-6f

__global__ __launch_bounds__(1024) void prep_once_kernel(
    const float* __restrict__ x, const int* __restrict__ bus_type,
    const float* __restrict__ br_r, const float* __restrict__ br_x,
    float* va, float* vm, float* gsa, float* bsa, int* kmap, int* m_dev) {
  __shared__ int cnt[1024];
  const int tid = threadIdx.x;
  int kept[4];
  int c = 0;
#pragma unroll
  for (int k = 0; k < 4; ++k) {
    int j = tid * 4 + k;
    kept[k] = 0;
    if (j < N2) {
      bool kp = (j < N_BUS) ? (bus_type[j] != 3) : (bus_type[j - N_BUS] == 1);
      kept[k] = kp ? 1 : 0;
      c += kept[k];
    }
  }
  cnt[tid] = c;
  __syncthreads();
  for (int off = 1; off < 1024; off <<= 1) {
    int v = cnt[tid];
    int u = (tid >= off) ? cnt[tid - off] : 0;
    __syncthreads();
    cnt[tid] = v + u;
    __syncthreads();
  }
  int base = cnt[tid] - c;  // exclusive prefix
#pragma unroll
  for (int k = 0; k < 4; ++k) {
    int j = tid * 4 + k;
    if (j < N2) kmap[j] = kept[k] ? base++ : -1;
  }
  if (tid == 1023) *m_dev = cnt[1023];
  for (int e = tid; e < N_EDGE; e += 1024) {
    float r = br_r[e], xx = br_x[e];
    float den = r * r + xx * xx;
    gsa[e] = r / den;
    bsa[e] = -xx / den;
  }
  for (int i = tid; i < N_BUS; i += 1024) {
    va[i] = x[i];
    vm[i] = x[N_BUS + i];
  }
}

__global__ void step_prep_kernel(const int* __restrict__ bus_type,
                                 const float* __restrict__ vsp,
                                 const float* __restrict__ va,
                                 const float* __restrict__ vm,
                                 float* dxc, float* Pacc, float* Qacc) {
  int t = blockIdx.x * blockDim.x + threadIdx.x;
  if (t >= N2) return;
  if (t < N_BUS) {
    Pacc[t] = 0.f;
    Qacc[t] = 0.f;
    int bt = bus_type[t];
    dxc[t] = (bt == 3) ? va[t] / (1.f + EPSR) : 0.f;
  } else {
    int i = t - N_BUS;
    int bt = bus_type[i];
    dxc[t] = (bt >= 2) ? (vm[i] - vsp[i]) / (1.f + EPSR) : 0.f;
  }
}

__global__ void clear_M_kernel(float4* __restrict__ M4) {
  int t = blockIdx.x * blockDim.x + threadIdx.x;
  if (t < MPAD * LD / 4) M4[t] = float4{0.f, 0.f, 0.f, 0.f};
}

__device__ __forceinline__ void addJ(float* __restrict__ M,
                                     const int* __restrict__ kmap,
                                     const float* __restrict__ dxc, int r,
                                     int C, float v) {
  int c = kmap[C];
  if (c >= 0)
    atomicAdd(&M[(size_t)r * LD + c], v);
  else
    atomicAdd(&M[(size_t)r * LD + MPAD], -v * dxc[C]);
}

__global__ void edge_kernel(const int* __restrict__ ei,
                            const float* __restrict__ gsa,
                            const float* __restrict__ bsa,
                            const float* __restrict__ g_fr,
                            const float* __restrict__ b_fr,
                            const float* __restrict__ g_to,
                            const float* __restrict__ b_to,
                            const float* __restrict__ tapA,
                            const float* __restrict__ shiftA,
                            const float* __restrict__ va,
                            const float* __restrict__ vm,
                            const int* __restrict__ kmap,
                            const float* __restrict__ dxc,
                            float* __restrict__ M, float* __restrict__ Pacc,
                            float* __restrict__ Qacc) {
  int e = blockIdx.x * blockDim.x + threadIdx.x;
  if (e >= N_EDGE) return;
  int s = ei[e], d = ei[N_EDGE + e];
  float g = gsa[e], b = bsa[e];
  float ti = 1.f / tapA[e];
  float vi = vm[s], vj = vm[d];
  float th = (va[s] - va[d]) - shiftA[e];
  float cf = cosf(th), sf = sinf(th);
  float vij = vi * vj * ti;
  float Af = g * cf + b * sf, Bf = g * sf - b * cf;
  float At = g * cf - b * sf, Bt = -g * sf - b * cf;
  float vit = vi * ti;
  float Pf = vit * vit * (g + g_fr[e]) + vij * (-g * cf - b * sf);
  float Qf = -vit * vit * (b + b_fr[e]) + vij * (-g * sf + b * cf);
  float Pt = vj * vj * (g + g_to[e]) + vij * (-g * cf + b * sf);
  float Qt = -vj * vj * (b + b_to[e]) + vij * (g * sf + b * cf);
  atomicAdd(&Pacc[s], Pf);
  atomicAdd(&Qacc[s], Qf);
  atomicAdd(&Pacc[d], Pt);
  atomicAdd(&Qacc[d], Qt);
  int rPs = kmap[s], rPd = kmap[d];
  int rQs = kmap[N_BUS + s], rQd = kmap[N_BUS + d];
  if (rPs >= 0) {
    addJ(M, kmap, dxc, rPs, s, -vij * Bf);
    addJ(M, kmap, dxc, rPs, d, vij * Bf);
    addJ(M, kmap, dxc, rPs, N_BUS + s,
         -2.f * vi * ti * ti * (g + g_fr[e]) + vj * ti * Af);
    addJ(M, kmap, dxc, rPs, N_BUS + d, vi * ti * Af);
  }
  if (rQs >= 0) {
    addJ(M, kmap, dxc, rQs, s, vij * Af);
    addJ(M, kmap, dxc, rQs, d, -vij * Af);
    addJ(M, kmap, dxc, rQs, N_BUS + s,
         2.f * vi * ti * ti * (b + b_fr[e]) + vj * ti * Bf);
    addJ(M, kmap, dxc, rQs, N_BUS + d, vi * ti * Bf);
  }
  if (rPd >= 0) {
    addJ(M, kmap, dxc, rPd, d, -vij * Bt);
    addJ(M, kmap, dxc, rPd, s, vij * Bt);
    addJ(M, kmap, dxc, rPd, N_BUS + d,
         -2.f * vj * (g + g_to[e]) + vi * ti * At);
    addJ(M, kmap, dxc, rPd, N_BUS + s, vj * ti * At);
  }
  if (rQd >= 0) {
    addJ(M, kmap, dxc, rQd, d, vij * At);
    addJ(M, kmap, dxc, rQd, s, -vij * At);
    addJ(M, kmap, dxc, rQd, N_BUS + d,
         2.f * vj * (b + b_to[e]) + vi * ti * Bt);
    addJ(M, kmap, dxc, rQd, N_BUS + s, vj * ti * Bt);
  }
}

__global__ void finalize_kernel(const float* __restrict__ p_spec,
                                const float* __restrict__ q_spec,
                                const float* __restrict__ gsN,
                                const float* __restrict__ bsN,
                                const float* __restrict__ va,
                                const float* __restrict__ vm,
                                const int* __restrict__ kmap,
                                const float* __restrict__ dxc,
                                const int* __restrict__ m_dev,
                                float* __restrict__ M,
                                const float* __restrict__ Pacc,
                                const float* __restrict__ Qacc) {
  int t = blockIdx.x * blockDim.x + threadIdx.x;
  if (t < N_BUS) {
    int r = kmap[t];
    if (r >= 0) {
      float* row = &M[(size_t)r * LD];
      row[r] += EPSR;
      int cq = kmap[N_BUS + t];
      float val = -2.f * vm[t] * gsN[t];
      if (cq >= 0)
        row[cq] += val;
      else
        row[MPAD] -= val * dxc[N_BUS + t];
      float Pc = Pacc[t] + vm[t] * vm[t] * gsN[t];
      row[MPAD] += p_spec[t] - Pc;
    }
  } else if (t < N2) {
    int i = t - N_BUS;
    int r = kmap[t];
    if (r >= 0) {
      float* row = &M[(size_t)r * LD];
      row[r] += 2.f * vm[i] * bsN[i] + EPSR;
      float Qc = Qacc[i] - vm[i] * vm[i] * bsN[i];
      row[MPAD] += q_spec[i] - Qc;
    }
  } else if (t < N2 + MPAD) {
    int r = t - N2;
    if (r >= *m_dev) M[(size_t)r * LD + r] = 1.f;
  }
}

// In-LDS no-pivot LU of a 64x64 tile (stride 68). 256 threads.
__device__ __forceinline__ void lu64_nopivot(float (*A)[68], int tid) {
#pragma unroll 1
  for (int k = 0; k < 63; ++k) {
    float dinv = 1.f / A[k][k];
    if (tid > k && tid < 64) A[tid][k] *= dinv;
    __syncthreads();
    int c = tid & 63, q = tid >> 6;
    if (c > k) {
      float ukc = A[k][c];
      for (int r = k + 1 + q; r < 64; r += 4)
        A[r][c] = fmaf(-A[r][k], ukc, A[r][c]);
    }
    __syncthreads();
  }
}

__global__ __launch_bounds__(256) void factor0_kernel(float* __restrict__ M) {
  __shared__ __align__(16) float A[64][68];
  const int tid = threadIdx.x;
  for (int idx = tid; idx < 64 * 16; idx += 256) {
    int i = idx >> 4, j4 = idx & 15;
    *(float4*)&A[i][j4 * 4] = *(const float4*)&M[(size_t)i * LD + j4 * 4];
  }
  __syncthreads();
  lu64_nopivot(A, tid);
  for (int idx = tid; idx < 64 * 64; idx += 256)
    M[(size_t)(idx >> 6) * LD + DCOL + (idx & 63)] = A[idx >> 6][idx & 63];
}

// TRSM for panel `pan`: 64-thread blocks.
//  blocks [0, ncb)   : forward-solve trailing columns (incl RHS) with unit-L
//  blocks [ncb, ...) : solve L21 rows (X * U = A)
__global__ __launch_bounds__(64) void trsm_kernel(float* __restrict__ M,
                                                  int pan, int ncb) {
  const int s0 = pan * NB, s1 = s0 + NB;
  const int tid = threadIdx.x;
  __shared__ __align__(16) float Ls[64][68];
  __shared__ float sDi[64];
  for (int k = 0; k < 16; ++k) {
    int idx = tid + 64 * k;
    int i = idx >> 4, j4 = idx & 15;
    *(float4*)&Ls[i][j4 * 4] =
        *(const float4*)&M[(size_t)(s0 + i) * LD + DCOL + j4 * 4];
  }
  __syncthreads();
  sDi[tid] = 1.f / Ls[tid][tid];
  __syncthreads();

  if (blockIdx.x < ncb) {
    int cc = s1 + blockIdx.x * 64 + tid;
    if (cc <= MPAD) {
      float y[64];
#pragma unroll
      for (int i = 0; i < 64; ++i) y[i] = M[(size_t)(s0 + i) * LD + cc];
#pragma unroll
      for (int i4 = 0; i4 < 16; ++i4) {
        const int i0 = i4 * 4;
        float a0 = y[i0], a1 = y[i0 + 1], a2 = y[i0 + 2], a3 = y[i0 + 3];
#pragma unroll
        for (int j4 = 0; j4 < i4; ++j4) {
          const int j0 = j4 * 4;
          float yj0 = y[j0], yj1 = y[j0 + 1], yj2 = y[j0 + 2], yj3 = y[j0 + 3];
          float4 l0 = *(const float4*)&Ls[i0 + 0][j0];
          float4 l1 = *(const float4*)&Ls[i0 + 1][j0];
          float4 l2 = *(const float4*)&Ls[i0 + 2][j0];
          float4 l3 = *(const float4*)&Ls[i0 + 3][j0];
          a0 = fmaf(-l0.x, yj0, fmaf(-l0.y, yj1, fmaf(-l0.z, yj2, fmaf(-l0.w, yj3, a0))));
          a1 = fmaf(-l1.x, yj0, fmaf(-l1.y, yj1, fmaf(-l1.z, yj2, fmaf(-l1.w, yj3, a1))));
          a2 = fmaf(-l2.x, yj0, fmaf(-l2.y, yj1, fmaf(-l2.z, yj2, fmaf(-l2.w, yj3, a2))));
          a3 = fmaf(-l3.x, yj0, fmaf(-l3.y, yj1, fmaf(-l3.z, yj2, fmaf(-l3.w, yj3, a3))));
        }
        a1 = fmaf(-Ls[i0 + 1][i0], a0, a1);
        a2 = fmaf(-Ls[i0 + 2][i0], a0, fmaf(-Ls[i0 + 2][i0 + 1], a1, a2));
        a3 = fmaf(-Ls[i0 + 3][i0], a0,
                  fmaf(-Ls[i0 + 3][i0 + 1], a1, fmaf(-Ls[i0 + 3][i0 + 2], a2, a3)));
        y[i0] = a0; y[i0 + 1] = a1; y[i0 + 2] = a2; y[i0 + 3] = a3;
      }
#pragma unroll
      for (int i = 0; i < 64; ++i) M[(size_t)(s0 + i) * LD + cc] = y[i];
    }
  } else {
    int r = s1 + (blockIdx.x - ncb) * 64 + tid;
    if (r < MPAD) {
      float a[64];
#pragma unroll
      for (int j4 = 0; j4 < 16; ++j4) {
        float4 t = *(const float4*)&M[(size_t)r * LD + s0 + j4 * 4];
        a[j4 * 4] = t.x; a[j4 * 4 + 1] = t.y;
        a[j4 * 4 + 2] = t.z; a[j4 * 4 + 3] = t.w;
      }
#pragma unroll
      for (int j4 = 0; j4 < 16; ++j4) {
        const int j0 = j4 * 4;
        float b0_ = a[j0], b1 = a[j0 + 1], b2 = a[j0 + 2], b3 = a[j0 + 3];
#pragma unroll
        for (int k4 = 0; k4 < j4; ++k4) {
#pragma unroll
          for (int dk = 0; dk < 4; ++dk) {
            float xk = a[k4 * 4 + dk];
            float4 u = *(const float4*)&Ls[k4 * 4 + dk][j0];
            b0_ = fmaf(-xk, u.x, b0_);
            b1 = fmaf(-xk, u.y, b1);
            b2 = fmaf(-xk, u.z, b2);
            b3 = fmaf(-xk, u.w, b3);
          }
        }
        b0_ *= sDi[j0];
        b1 = fmaf(-b0_, Ls[j0][j0 + 1], b1) * sDi[j0 + 1];
        b2 = fmaf(-b0_, Ls[j0][j0 + 2], fmaf(-b1, Ls[j0 + 1][j0 + 2], b2)) *
             sDi[j0 + 2];
        b3 = fmaf(-b0_, Ls[j0][j0 + 3],
                  fmaf(-b1, Ls[j0 + 1][j0 + 3],
                       fmaf(-b2, Ls[j0 + 2][j0 + 3], b3))) *
             sDi[j0 + 3];
        a[j0] = b0_; a[j0 + 1] = b1; a[j0 + 2] = b2; a[j0 + 3] = b3;
      }
#pragma unroll
      for (int j4 = 0; j4 < 16; ++j4) {
        float4 t{a[j4 * 4], a[j4 * 4 + 1], a[j4 * 4 + 2], a[j4 * 4 + 3]};
        *(float4*)&M[(size_t)r * LD + s0 + j4 * 4] = t;
      }
    }
  }
}

// Trailing update C -= L21*U12; block (0,0) also factors the next diag tile.
__global__ __launch_bounds__(256) void gemm_kernel(float* __restrict__ M,
                                                   int pan) {
  const int s0 = pan * NB, s1 = s0 + NB;
  const int r0 = s1 + blockIdx.x * 64;
  const int c0 = s1 + blockIdx.y * 64;
  __shared__ __align__(16) float As[64][68];
  __shared__ __align__(16) float Bs[64][68];
  const int tid = threadIdx.x;
  for (int idx = tid; idx < 64 * 16; idx += 256) {
    int i = idx >> 4, j4 = idx & 15;
    *(float4*)&As[i][j4 * 4] =
        *(const float4*)&M[(size_t)(r0 + i) * LD + s0 + j4 * 4];
    *(float4*)&Bs[i][j4 * 4] =
        *(const float4*)&M[(size_t)(s0 + i) * LD + c0 + j4 * 4];
  }
  __syncthreads();
  const int tr = (tid >> 4) * 4;
  const int tc = (tid & 15) * 4;
  float acc[4][4] = {};
#pragma unroll
  for (int k4 = 0; k4 < 16; ++k4) {
    float ar[4][4], br[4][4];
#pragma unroll
    for (int i = 0; i < 4; ++i) {
      float4 t = *(const float4*)&As[tr + i][k4 * 4];
      ar[i][0] = t.x; ar[i][1] = t.y; ar[i][2] = t.z; ar[i][3] = t.w;
    }
#pragma unroll
    for (int kk = 0; kk < 4; ++kk) {
      float4 t = *(const float4*)&Bs[k4 * 4 + kk][tc];
      br[kk][0] = t.x; br[kk][1] = t.y; br[kk][2] = t.z; br[kk][3] = t.w;
    }
#pragma unroll
    for (int kk = 0; kk < 4; ++kk)
#pragma unroll
      for (int i = 0; i < 4; ++i)
#pragma unroll
        for (int jj = 0; jj < 4; ++jj)
          acc[i][jj] = fmaf(ar[i][kk], br[kk][jj], acc[i][jj]);
  }
  __syncthreads();  // As/Bs reads complete (allows As reuse below)
  const bool fb = (blockIdx.x == 0 && blockIdx.y == 0);
  const bool lastc = (c0 == MPAD);
#pragma unroll
  for (int i = 0; i < 4; ++i) {
    float* crow = &M[(size_t)(r0 + tr + i) * LD + c0 + tc];
    float4 cv = *(float4*)crow;
    cv.x -= acc[i][0];
    cv.y -= acc[i][1];
    cv.z -= acc[i][2];
    cv.w -= acc[i][3];
    if (!lastc) {
      *(float4*)crow = cv;
    } else {
      // only columns <= MPAD are real (col MPAD == RHS); don't clobber DCOL
      if (c0 + tc + 0 <= MPAD) crow[0] = cv.x;
      if (c0 + tc + 1 <= MPAD) crow[1] = cv.y;
      if (c0 + tc + 2 <= MPAD) crow[2] = cv.z;
      if (c0 + tc + 3 <= MPAD) crow[3] = cv.w;
    }
    if (fb) {
      As[tr + i][tc + 0] = cv.x;
      As[tr + i][tc + 1] = cv.y;
      As[tr + i][tc + 2] = cv.z;
      As[tr + i][tc + 3] = cv.w;
    }
  }
  if (fb) {
    __syncthreads();
    lu64_nopivot(As, tid);
    for (int idx = tid; idx < 64 * 64; idx += 256)
      M[(size_t)(s1 + (idx >> 6)) * LD + DCOL + (idx & 63)] =
          As[idx >> 6][idx & 63];
  }
}

__global__ __launch_bounds__(1024) void backsub_kernel(
    const float* __restrict__ M, float* __restrict__ dx) {
  __shared__ float ys[MPAD];
  __shared__ __align__(16) float Ds[64][68];
  __shared__ float sDi[64];
  const int tid = threadIdx.x;
  for (int r = tid; r < MPAD; r += 1024) ys[r] = M[(size_t)r * LD + MPAD];
  __syncthreads();
  for (int jb = NPANELS - 1; jb >= 0; --jb) {
    const int b0 = jb * NB;
    for (int idx = tid; idx < 64 * 16; idx += 1024) {
      int i = idx >> 4, j4 = idx & 15;
      *(float4*)&Ds[i][j4 * 4] =
          *(const float4*)&M[(size_t)(b0 + i) * LD + DCOL + j4 * 4];
    }
    __syncthreads();
    if (tid < 64) sDi[tid] = 1.f / Ds[tid][tid];
    __syncthreads();
    if (tid < 64) {  // wave 0: serial backward solve on this 64-block
      for (int i = 63; i >= 0; --i) {
        float xv = ys[b0 + i] * sDi[i];
        if (tid == i) ys[b0 + i] = xv;
        if (tid < i) ys[b0 + tid] = fmaf(-Ds[tid][i], xv, ys[b0 + tid]);
      }
    }
    __syncthreads();
    if (b0 > 0) {
      const int q = tid & 15;
      float4 xq = *(const float4*)&ys[b0 + q * 4];
      for (int r = (tid >> 4); r < b0; r += 64) {
        float4 u = *(const float4*)&M[(size_t)r * LD + b0 + q * 4];
        float p = u.x * xq.x + u.y * xq.y + u.z * xq.z + u.w * xq.w;
        p += __shfl_down(p, 8, 16);
        p += __shfl_down(p, 4, 16);
        p += __shfl_down(p, 2, 16);
        p += __shfl_down(p, 1, 16);
        if (q == 0) ys[r] -= p;
      }
    }
    __syncthreads();
  }
  for (int r = tid; r < MPAD; r += 1024) dx[r] = ys[r];
}

__global__ void update_kernel(const int* __restrict__ kmap,
                              const float* __restrict__ dx,
                              const float* __restrict__ dxc, float* va,
                              float* vm, float* __restrict__ out) {
  int t = blockIdx.x * blockDim.x + threadIdx.x;
  if (t >= N2) return;
  int r = kmap[t];
  float d = (r >= 0) ? dx[r] : dxc[t];
  if (t < N_BUS) {
    float v = va[t] - d;
    va[t] = v;
    out[t] = v;
  } else {
    int i = t - N_BUS;
    float v = vm[i] - d;
    v = fminf(fmaxf(v, 0.5f), 1.5f);
    vm[i] = v;
    out[t] = v;
  }
}

extern "C" void kernel_launch(void* const* d_in, const int* in_sizes, int n_in,
                              void* d_out, int out_size, void* d_ws,
                              size_t ws_size, hipStream_t stream) {
  const float* x = (const float*)d_in[0];
  const int* ei = (const int*)d_in[1];
  const float* br_r = (const float*)d_in[2];
  const float* br_x = (const float*)d_in[3];
  const float* g_fr = (const float*)d_in[4];
  const float* b_fr = (const float*)d_in[5];
  const float* g_to = (const float*)d_in[6];
  const float* b_to = (const float*)d_in[7];
  const float* tap = (const float*)d_in[8];
  const float* shift = (const float*)d_in[9];
  const float* p_spec = (const float*)d_in[10];
  const float* q_spec = (const float*)d_in[11];
  const float* gsN = (const float*)d_in[12];
  const float* bsN = (const float*)d_in[13];
  const int* bus_type = (const int*)d_in[14];
  const float* vsp = (const float*)d_in[15];
  float* out = (float*)d_out;

  float* W = (float*)d_ws;
  float* M = W;
  float* dx = W + (size_t)MPAD * LD;
  float* dxc = dx + MPAD;
  float* va = dxc + N2;
  float* vm = va + N_BUS;
  float* Pacc = vm + N_BUS;
  float* Qacc = Pacc + N_BUS;
  float* gsa = Qacc + N_BUS;
  float* bsa = gsa + N_EDGE;
  int* kmap = (int*)(bsa + N_EDGE);
  int* m_dev = kmap + N2;

  prep_once_kernel<<<1, 1024, 0, stream>>>(x, bus_type, br_r, br_x, va, vm,
                                           gsa, bsa, kmap, m_dev);
  for (int t = 0; t < T_STEPS; ++t) {
    step_prep_kernel<<<(N2 + 255) / 256, 256, 0, stream>>>(bus_type, vsp, va,
                                                           vm, dxc, Pacc, Qacc);
    clear_M_kernel<<<(MPAD * LD / 4 + 255) / 256, 256, 0, stream>>>(
        (float4*)M);
    edge_kernel<<<(N_EDGE + 255) / 256, 256, 0, stream>>>(
        ei, gsa, bsa, g_fr, b_fr, g_to, b_to, tap, shift, va, vm, kmap, dxc, M,
        Pacc, Qacc);
    finalize_kernel<<<(N2 + MPAD + 255) / 256, 256, 0, stream>>>(
        p_spec, q_spec, gsN, bsN, va, vm, kmap, dxc, m_dev, M, Pacc, Qacc);
    factor0_kernel<<<1, 256, 0, stream>>>(M);
    for (int p = 0; p < NPANELS; ++p) {
      int s1 = (p + 1) * NB;
      int w = MPAD - s1 + 1;            // trailing cols incl RHS
      int ncb = (w + 63) / 64;
      int nrb = (MPAD - s1 + 63) / 64;  // rows below
      trsm_kernel<<<ncb + nrb, 64, 0, stream>>>(M, p, ncb);
      int tr_ = NPANELS - 1 - p;
      int tc_ = NPANELS - p;
      if (tr_ > 0) {
        dim3 g(tr_, tc_);
        gemm_kernel<<<g, 256, 0, stream>>>(M, p);
      }
    }
    backsub_kernel<<<1, 1024, 0, stream>>>(M, dx);
    update_kernel<<<(N2 + 255) / 256, 256, 0, stream>>>(kmap, dx, dxc, va, vm,
                                                        out);
  }
}